// Round 1
// baseline (1579.693 us; speedup 1.0000x reference)
//
#include <hip/hip_runtime.h>

// np.float32(np.pi / 180)
#define PI180F 0.017453292519943295f

// ---------------------------------------------------------------------------
// Rotation matrix, matching the reference's (Rz @ Ry) @ Rx in fp32.
// ---------------------------------------------------------------------------
__device__ __forceinline__ void compute_R(const float th[6], float R[9], float t[3]) {
    float ax = th[0] * PI180F, ay = th[1] * PI180F, az = th[2] * PI180F;
    float cx = cosf(ax), sx = sinf(ax);
    float cy = cosf(ay), sy = sinf(ay);
    float cz = cosf(az), sz = sinf(az);
    // (Rz@Ry) = [[cz*cy, -sz, cz*sy],[sz*cy, cz, sz*sy],[-sy, 0, cy]]
    R[0] = cz * cy;  R[1] = (cz * sy) * sx - sz * cx;  R[2] = (cz * sy) * cx + sz * sx;
    R[3] = sz * cy;  R[4] = (sz * sy) * sx + cz * cx;  R[5] = (sz * sy) * cx - cz * sx;
    R[6] = -sy;      R[7] = cy * sx;                   R[8] = cy * cx;
    t[0] = th[3]; t[1] = th[4]; t[2] = th[5];
}

// ---------------------------------------------------------------------------
// Trilinear sample matching jax.scipy.ndimage.map_coordinates(order=1,
// mode='constant', cval=0): floor/ceil per axis, corner valid-mask, weights
// multiplied left-assoc, corners summed in itertools.product order.
// ---------------------------------------------------------------------------
__device__ __forceinline__ float tri_sample(const float* __restrict__ vol, int D,
                                             float c0, float c1, float c2) {
    float f0 = floorf(c0), f1 = floorf(c1), f2 = floorf(c2);
    int i0 = (int)f0, i1 = (int)f1, i2 = (int)f2;
    float t0 = c0 - f0, t1 = c1 - f1, t2 = c2 - f2;
    float w0[2] = {1.0f - t0, t0};
    float w1[2] = {1.0f - t1, t1};
    float w2[2] = {1.0f - t2, t2};
    float acc = 0.0f;
#pragma unroll
    for (int a = 0; a < 2; ++a) {
        int ia = i0 + a;
        bool va = (ia >= 0) && (ia < D);
#pragma unroll
        for (int b = 0; b < 2; ++b) {
            int ib = i1 + b;
            bool vb = (ib >= 0) && (ib < D);
#pragma unroll
            for (int c = 0; c < 2; ++c) {
                int ic = i2 + c;
                bool vc = (ic >= 0) && (ic < D);
                float val = (va && vb && vc) ? vol[(ia * D + ib) * D + ic] : 0.0f;
                acc += ((w0[a] * w1[b]) * w2[c]) * val;
            }
        }
    }
    return acc;
}

// ---------------------------------------------------------------------------
// Eval kernel: computes partial SSE sums for warped(src, theta) vs tgt.
// fd=1: 13 configs per row (c=0 base, c=1..6 +ss*e_j, c=7..12 -ss*e_j).
// fd=0: 1 config per row (theta pointer = theta_try).
// grid.x = nconf*8*K; block handles contiguous voxel chunk, fp64 tree-reduce.
// ---------------------------------------------------------------------------
__global__ __launch_bounds__(256) void eval_kernel(
    const float* __restrict__ src, const float* __restrict__ tgt,
    const float* __restrict__ theta, const int* __restrict__ active,
    double* __restrict__ partials, int D, int K, float ss, int fd)
{
    int gb = blockIdx.x;
    int k = gb % K;
    int e = gb / K;          // e = c*8 + b
    int b = e & 7;
    int c = fd ? (e >> 3) : 0;
    if (!active[b]) return;

    float th[6];
#pragma unroll
    for (int j = 0; j < 6; ++j) th[j] = theta[b * 6 + j];
    if (c > 0) {
        int j = (c - 1) % 6;
        th[j] += (c <= 6) ? ss : -ss;
    }
    float R[9], t[3];
    compute_R(th, R, t);

    int logD = (D == 64) ? 6 : ((D == 32) ? 5 : 4);
    int n = D * D * D;
    int chunk = n / K;
    int vstart = k * chunk;
    float step = 2.0f / (float)(D - 1);
    float scale = (float)(D - 1) * 0.5f;
    const float* s = src + (size_t)b * n;
    const float* g = tgt + (size_t)b * n;

    double acc = 0.0;
    for (int v = vstart + threadIdx.x; v < vstart + chunk; v += 256) {
        int kk = v & (D - 1);
        int jj = (v >> logD) & (D - 1);
        int ii = v >> (2 * logD);
        float x0 = -1.0f + (float)ii * step;
        float x1 = -1.0f + (float)jj * step;
        float x2 = -1.0f + (float)kk * step;
        float p0 = R[0] * x0 + R[1] * x1 + R[2] * x2 + t[0];
        float p1 = R[3] * x0 + R[4] * x1 + R[5] * x2 + t[1];
        float p2 = R[6] * x0 + R[7] * x1 + R[8] * x2 + t[2];
        float c0 = (p0 + 1.0f) * scale;
        float c1 = (p1 + 1.0f) * scale;
        float c2 = (p2 + 1.0f) * scale;
        float w = tri_sample(s, D, c0, c1, c2);
        float d = w - g[v];
        acc += (double)(d * d);
    }

    __shared__ double red[256];
    red[threadIdx.x] = acc;
    __syncthreads();
#pragma unroll
    for (int st = 128; st > 0; st >>= 1) {
        if (threadIdx.x < st) red[threadIdx.x] += red[threadIdx.x + st];
        __syncthreads();
    }
    if (threadIdx.x == 0) partials[(size_t)e * K + k] = red[0];
}

// ---------------------------------------------------------------------------
// update1: reduce 13x8 losses, record loss_all/loss_base, grad + momentum,
// normalized direction, theta_try.
// ---------------------------------------------------------------------------
__global__ void update1_kernel(const float* __restrict__ theta,
                               float* __restrict__ theta_try,
                               float* __restrict__ buf,
                               float* __restrict__ loss_base,
                               float* __restrict__ loss_all,
                               const int* __restrict__ active,
                               const double* __restrict__ partials,
                               int K, int n, float ss, int has_buf)
{
    __shared__ float lossf[104];
    int t = threadIdx.x;
    if (t < 104) {
        double s = 0.0;
        for (int i = 0; i < K; ++i) s += partials[(size_t)t * K + i];
        lossf[t] = (float)(s / (double)n);
    }
    __syncthreads();
    if (t < 8) {
        int b = t;
        if (active[b]) {
            float lb = lossf[b];        // c = 0
            loss_all[b] = lb;
            loss_base[b] = lb;
            float ub[6];
            for (int j = 0; j < 6; ++j) {
                float gpos = lossf[(1 + j) * 8 + b];
                float gneg = lossf[(7 + j) * 8 + b];
                float grad = gpos - gneg;
                float u = has_buf ? (buf[b * 6 + j] * 0.1f + grad) : grad;
                buf[b * 6 + j] = u;
                ub[j] = u;
            }
            float ss2 = 0.0f;
            for (int j = 0; j < 6; ++j) ss2 += ub[j] * ub[j];
            float denom = sqrtf(ss2) + 1e-6f;
            for (int j = 0; j < 6; ++j) {
                float d = ub[j] / denom;
                theta_try[b * 6 + j] = theta[b * 6 + j] - ss * d;
            }
        }
    }
}

// ---------------------------------------------------------------------------
// update2: reduce loss_new, accept/reject, deactivate.
// ---------------------------------------------------------------------------
__global__ void update2_kernel(float* __restrict__ theta,
                               const float* __restrict__ theta_try,
                               const float* __restrict__ loss_base,
                               int* __restrict__ active,
                               const double* __restrict__ partials,
                               int K, int n)
{
    int b = threadIdx.x;
    if (b < 8 && active[b]) {
        double s = 0.0;
        for (int i = 0; i < K; ++i) s += partials[(size_t)b * K + i];
        float ln = (float)(s / (double)n);
        if (ln + 1e-4f < loss_base[b]) {
            for (int j = 0; j < 6; ++j) theta[b * 6 + j] = theta_try[b * 6 + j];
        } else {
            active[b] = 0;
        }
    }
}

// ---------------------------------------------------------------------------
// Pool: mean over f^3 blocks (B=8, input D=64).
// ---------------------------------------------------------------------------
__global__ void pool_kernel(const float* __restrict__ in, float* __restrict__ out, int f)
{
    int Do = 64 / f;
    int n = 8 * Do * Do * Do;
    int idx = blockIdx.x * blockDim.x + threadIdx.x;
    if (idx >= n) return;
    int kk = idx % Do;
    int jj = (idx / Do) % Do;
    int ii = (idx / (Do * Do)) % Do;
    int b  = idx / (Do * Do * Do);
    const float* v = in + (size_t)b * 64 * 64 * 64;
    double s = 0.0;
    for (int a = 0; a < f; ++a)
        for (int b2 = 0; b2 < f; ++b2)
            for (int c = 0; c < f; ++c)
                s += (double)v[((ii * f + a) * 64 + (jj * f + b2)) * 64 + (kk * f + c)];
    out[idx] = (float)(s / (double)(f * f * f));
}

__global__ void init_theta_kernel(const float* __restrict__ theta_in,
                                  float* __restrict__ theta_deg)
{
    int t = threadIdx.x;
    if (t < 48) {
        int j = t % 6;
        float d2r = (j < 3) ? PI180F : 1.0f;
        theta_deg[t] = theta_in[t] / d2r;
    }
}

__global__ void step_init_kernel(int* __restrict__ active)
{
    if (threadIdx.x < 8) active[threadIdx.x] = 1;
}

__global__ void finalize_kernel(const float* __restrict__ theta0,
                                const float* __restrict__ theta_deg,
                                const float* __restrict__ loss_all,
                                float* __restrict__ out)
{
    int t = threadIdx.x;
    if (t < 48) {
        int j = t % 6;
        float d2r = (j < 3) ? PI180F : 1.0f;
        float td = theta_deg[t] * d2r;
        float dt = td - theta0[t];
        out[t] = theta0[t] + dt;
    } else if (t < 56) {
        out[t] = loss_all[t - 48];
    }
}

// ---------------------------------------------------------------------------
extern "C" void kernel_launch(void* const* d_in, const int* in_sizes, int n_in,
                              void* d_out, int out_size, void* d_ws, size_t ws_size,
                              hipStream_t stream)
{
    const float* theta0 = (const float*)d_in[0];
    const float* source = (const float*)d_in[1];
    const float* target = (const float*)d_in[2];
    float* out = (float*)d_out;

    char* ws = (char*)d_ws;
    size_t off = 0;
    auto alloc = [&](size_t bytes) -> void* {
        off = (off + 255) & ~(size_t)255;
        void* p = ws + off;
        off += bytes;
        return p;
    };
    float*  theta  = (float*)alloc(48 * 4);
    float*  ttry   = (float*)alloc(48 * 4);
    float*  buf    = (float*)alloc(48 * 4);
    float*  lbase  = (float*)alloc(8 * 4);
    float*  lall   = (float*)alloc(8 * 4);
    int*    active = (int*)alloc(8 * 4);
    double* pA     = (double*)alloc(104 * 32 * 8);
    double* pB     = (double*)alloc(8 * 128 * 8);
    float*  src2   = (float*)alloc((size_t)8 * 32768 * 4);
    float*  tgt2   = (float*)alloc((size_t)8 * 32768 * 4);
    float*  src4   = (float*)alloc((size_t)8 * 4096 * 4);
    float*  tgt4   = (float*)alloc((size_t)8 * 4096 * 4);

    pool_kernel<<<(8 * 32768 + 255) / 256, 256, 0, stream>>>(source, src2, 2);
    pool_kernel<<<(8 * 32768 + 255) / 256, 256, 0, stream>>>(target, tgt2, 2);
    pool_kernel<<<(8 * 4096 + 255) / 256, 256, 0, stream>>>(source, src4, 4);
    pool_kernel<<<(8 * 4096 + 255) / 256, 256, 0, stream>>>(target, tgt4, 4);

    init_theta_kernel<<<1, 64, 0, stream>>>(theta0, theta);

    struct Lv { const float* s; const float* g; int D; int K; int K3; float ss0; };
    Lv lvs[3] = {
        { src4,   tgt4,   16,  2,   8,  8.0f },
        { src2,   tgt2,   32,  8,  32,  4.0f },
        { source, target, 64, 32, 128,  2.0f },
    };

    for (int L = 0; L < 3; ++L) {
        Lv lv = lvs[L];
        int n = lv.D * lv.D * lv.D;
        float ssv = lv.ss0;
        for (int s = 0; s < 4; ++s) {
            step_init_kernel<<<1, 64, 0, stream>>>(active);
            for (int it = 0; it < 10; ++it) {
                int has_buf = (s == 0 && it == 0) ? 0 : 1;
                eval_kernel<<<13 * 8 * lv.K, 256, 0, stream>>>(
                    lv.s, lv.g, theta, active, pA, lv.D, lv.K, ssv, 1);
                update1_kernel<<<1, 128, 0, stream>>>(
                    theta, ttry, buf, lbase, lall, active, pA, lv.K, n, ssv, has_buf);
                eval_kernel<<<8 * lv.K3, 256, 0, stream>>>(
                    lv.s, lv.g, ttry, active, pB, lv.D, lv.K3, 0.0f, 0);
                update2_kernel<<<1, 64, 0, stream>>>(
                    theta, ttry, lbase, active, pB, lv.K3, n);
            }
            ssv *= 0.5f;
        }
    }

    finalize_kernel<<<1, 64, 0, stream>>>(theta0, theta, lall, out);
}